// Round 3
// baseline (247.099 us; speedup 1.0000x reference)
//
#include <hip/hip_runtime.h>
#include <hip/hip_bf16.h>

#define EMBED 256
#define NH 8
#define NL 4
#define NP 4
#define HD 32
#define BS 4
#define NQ 4000
#define NV 13294

using f32x4   = __attribute__((ext_vector_type(4))) float;
using bf16x8  = __attribute__((ext_vector_type(8))) short;

__device__ __forceinline__ float bf2f_lo(unsigned u) {
    union { unsigned u; float f; } x; x.u = u << 16; return x.f;
}
__device__ __forceinline__ float bf2f_hi(unsigned u) {
    union { unsigned u; float f; } x; x.u = u & 0xffff0000u; return x.f;
}
__device__ __forceinline__ unsigned short f2bf(float f) {
    union { float f; unsigned u; } x; x.f = f;
    unsigned u = x.u;
    return (unsigned short)((u + 0x7fffu + ((u >> 16) & 1u)) >> 16);
}

// ---------- prep: weight transposes + bias concat only ----------
__global__ __launch_bounds__(256) void msda_prep_k(
    const float* __restrict__ W_val, const float* __restrict__ W_out,
    const float* __restrict__ W_off, const float* __restrict__ W_attn,
    const float* __restrict__ b_off, const float* __restrict__ b_attn,
    unsigned short* __restrict__ Wt_val, unsigned short* __restrict__ Wt_out,
    unsigned short* __restrict__ Wt_qa, float* __restrict__ b_qa)
{
    int i = blockIdx.x * 256 + threadIdx.x;      // 896 blocks -> 229,376 elems
    if (i < 384) b_qa[i] = (i < 256) ? b_off[i] : b_attn[i - 256];
    if (i < 65536) {
        int r = i >> 8, c = i & 255;
        Wt_val[c * 256 + r] = f2bf(W_val[i]);
    } else if (i < 131072) {
        int j = i - 65536, r = j >> 8, c = j & 255;
        Wt_out[c * 256 + r] = f2bf(W_out[j]);
    } else if (i < 229376) {
        int j = i - 131072;              // j = n*256 + k, n in [0,384)
        int n = j >> 8, k = j & 255;
        float v = (n < 256) ? W_off[k * 256 + n] : W_attn[k * 128 + (n - 256)];
        Wt_qa[j] = f2bf(v);
    }
}

// ---------- GEMM body: barrier-free, all-register fragment streaming ----------
// Fragment layout (per wave): A row = wm+mi*16+l16, cols quad*8..+8 -> the 4 quads
// of a wave cover one full 128B row-chunk => fully coalesced global loads.
// ABF16=false: A fp32, converted in-register. ABF16=true: A bf16, 16B loads.
// B loaded per-wave direct from Bt (128-192KB, L2/L3-resident; redundancy L1-served).
// K-loop: C=8 fully unrolled, software-prefetch depth 1; NO LDS, NO barriers ->
// no vmcnt(0) drain; compiler schedules counted vmcnt across unrolled chunks.
// EPI 0: bf16 [M][N] via LDS bounce (coalesced 16B row stores).
// EPI 1: fp32 [M][N] direct (col fragments are 64-128B/row per wave; HW coalesces).
template<int TM, int EPI, bool ABF16>
__device__ __forceinline__ void gemm_body(
    char* lds,
    const void* __restrict__ Ap,
    const unsigned short* __restrict__ Bt,
    const float* __restrict__ bias,
    void* __restrict__ out,
    int M, int N, int mblk, int nblk)
{
    constexpr int K = 256, C = 8;
    constexpr int NI = (TM == 128) ? 4 : 2;
    const int m0 = mblk * TM, n0 = nblk * 128;
    const int tid  = threadIdx.x;
    const int w    = tid >> 6;
    const int lane = tid & 63;
    const int quad = lane >> 4;
    const int l16  = lane & 15;
    const int wm   = (TM == 128) ? (w & 1) * 64 : 0;
    const int wn   = (TM == 128) ? (w >> 1) * 64 : w * 32;

    const float* apf[4];
    const unsigned short* apb[4];
#pragma unroll
    for (int mi = 0; mi < 4; mi++) {
        int r = min(m0 + wm + mi * 16 + l16, M - 1);
        if constexpr (ABF16) apb[mi] = (const unsigned short*)Ap + (size_t)r * K + quad * 8;
        else                 apf[mi] = (const float*)Ap + (size_t)r * K + quad * 8;
    }
    const unsigned short* bp[NI];
#pragma unroll
    for (int ni = 0; ni < NI; ni++)
        bp[ni] = Bt + (size_t)(n0 + wn + ni * 16 + l16) * K + quad * 8;

    f32x4 acc[4][NI];
#pragma unroll
    for (int a = 0; a < 4; a++)
#pragma unroll
        for (int b = 0; b < NI; b++) acc[a][b] = (f32x4){0.f, 0.f, 0.f, 0.f};

    float4 aLo[4], aHi[4];
    bf16x8 aPf[4], bPf[NI];
    auto fetchA = [&](int c) {
#pragma unroll
        for (int mi = 0; mi < 4; mi++) {
            if constexpr (ABF16) {
                aPf[mi] = *(const bf16x8*)(apb[mi] + c * 32);
            } else {
                aLo[mi] = *(const float4*)(apf[mi] + c * 32);
                aHi[mi] = *(const float4*)(apf[mi] + c * 32 + 4);
            }
        }
    };
    auto fetchB = [&](int c) {
#pragma unroll
        for (int ni = 0; ni < NI; ni++) bPf[ni] = *(const bf16x8*)(bp[ni] + c * 32);
    };

    fetchA(0); fetchB(0);
#pragma unroll
    for (int c = 0; c < C; c++) {
        bf16x8 af[4], bc[NI];
#pragma unroll
        for (int mi = 0; mi < 4; mi++) {
            if constexpr (ABF16) {
                af[mi] = aPf[mi];
            } else {
                bf16x8 t;
                t[0] = (short)f2bf(aLo[mi].x); t[1] = (short)f2bf(aLo[mi].y);
                t[2] = (short)f2bf(aLo[mi].z); t[3] = (short)f2bf(aLo[mi].w);
                t[4] = (short)f2bf(aHi[mi].x); t[5] = (short)f2bf(aHi[mi].y);
                t[6] = (short)f2bf(aHi[mi].z); t[7] = (short)f2bf(aHi[mi].w);
                af[mi] = t;
            }
        }
#pragma unroll
        for (int ni = 0; ni < NI; ni++) bc[ni] = bPf[ni];
        if (c + 1 < C) { fetchA(c + 1); fetchB(c + 1); }   // in flight across MFMA(c)
#pragma unroll
        for (int mi = 0; mi < 4; mi++)
#pragma unroll
            for (int ni = 0; ni < NI; ni++)
                acc[mi][ni] = __builtin_amdgcn_mfma_f32_16x16x32_bf16(af[mi], bc[ni], acc[mi][ni], 0, 0, 0);
    }

    if constexpr (EPI == 0) {
        // LDS bounce -> coalesced bf16 row stores (fixes 2x write amplification)
        unsigned short* cs = (unsigned short*)lds;      // [TM][136] bf16
#pragma unroll
        for (int ni = 0; ni < NI; ni++) {
            int cl = wn + ni * 16 + l16;
            float bvv = bias[n0 + cl];
#pragma unroll
            for (int mi = 0; mi < 4; mi++)
#pragma unroll
                for (int r = 0; r < 4; r++) {
                    int ml = wm + mi * 16 + quad * 4 + r;
                    cs[ml * 136 + cl] = f2bf(acc[mi][ni][r] + bvv);
                }
        }
        __syncthreads();
        const int row = tid >> 1, half = tid & 1;
        const int m = m0 + row;
        if (row < TM && m < M) {
            const uint4* s = (const uint4*)&cs[row * 136 + half * 64];
            uint4* d = (uint4*)((unsigned short*)out + (size_t)m * N + n0 + half * 64);
#pragma unroll
            for (int j = 0; j < 8; j++) d[j] = s[j];
        }
    } else {
#pragma unroll
        for (int ni = 0; ni < NI; ni++) {
            int cc = n0 + wn + ni * 16 + l16;
            float bvv = bias[cc];
#pragma unroll
            for (int mi = 0; mi < 4; mi++)
#pragma unroll
                for (int r = 0; r < 4; r++) {
                    int m = m0 + wm + mi * 16 + quad * 4 + r;
                    if (m >= M) continue;
                    ((float*)out)[(size_t)m * N + cc] = acc[mi][ni][r] + bvv;
                }
        }
    }
}

// ---------- merged value-GEMM + qa-GEMM: one dispatch, block-range split ----------
// value: 832 blocks (416 m x 2 n, TM=128, bf16 out via LDS bounce),
// qa: 750 blocks (250 m x 3 n, TM=64, fp32 out direct).
__global__ __launch_bounds__(256) void msda_gemm_vq_k(
    const float* __restrict__ value, const float* __restrict__ query,
    const unsigned short* __restrict__ Wt_val, const unsigned short* __restrict__ Wt_qa,
    const float* __restrict__ b_val, const float* __restrict__ b_qa,
    unsigned short* __restrict__ v_buf, float* __restrict__ oa_buf)
{
    extern __shared__ char lds[];
    const int bx = blockIdx.x;
    if (bx < 832) {
        gemm_body<128, 0, false>(lds, value, Wt_val, b_val, v_buf,
                                 BS * NV, 256, bx >> 1, bx & 1);
    } else {
        const int j = bx - 832;
        const int mb = j / 3;
        gemm_body<64, 1, false>(lds, query, Wt_qa, b_qa, oa_buf,
                                BS * NQ, 384, mb, j - mb * 3);
    }
}

// ---------- out GEMM (after sampler): A bf16 direct, no LDS at all ----------
__global__ __launch_bounds__(256) void msda_gemm_out_k(
    const unsigned short* __restrict__ t_buf,
    const unsigned short* __restrict__ Wt_out,
    const float* __restrict__ b_out,
    float* __restrict__ out)
{
    const int bx = blockIdx.x;
    gemm_body<64, 1, true>(nullptr, t_buf, Wt_out, b_out, out,
                           BS * NQ, 256, bx >> 1, bx & 1);
}

// ---------- sampler: 4 queries/block, wave = 1 query, thread = (h, 4-chan grp) ----------
__global__ __launch_bounds__(256) void msda_sampler_k(
    const float* __restrict__ refpts,            // (BS*NQ, 8) fp32
    const float* __restrict__ oa_buf,            // (BS*NQ, 384) fp32: off[256] | attn[128]
    const unsigned short* __restrict__ v_buf,    // (BS*NV, 256) bf16 row-major
    unsigned short* __restrict__ t_out)          // (BS*NQ, 256) bf16
{
    __shared__ float  oa_s[4][384];
    __shared__ float  ref_s[4][8];
    __shared__ float4 wtab[528];                 // idx = i*33 + ql*8 + h (stride-33 pad)
    __shared__ int4   itab[528];

    const int tid = threadIdx.x;
    const int q0  = blockIdx.x * 4;

    // phase 1: cooperative loads
    {
        const float4* src = (const float4*)(oa_buf + (size_t)q0 * 384);
        float4* dst = (float4*)&oa_s[0][0];
        dst[tid] = src[tid];
        if (tid < 128) dst[256 + tid] = src[256 + tid];
        if (tid < 32) ((float*)ref_s)[tid] = refpts[q0 * 8 + tid];
    }
    __syncthreads();

    // phase 2+3 fused: shuffle softmax (16 lanes = one (q,h) group) + tables
    const int HWs[4]    = {100, 50, 25, 13};
    const int starts[4] = {0, 10000, 12500, 13125};
#pragma unroll
    for (int it = 0; it < 2; it++) {
        int s  = tid + it * 256;                 // 0..511
        int i  = s & 15;                         // l*4+p
        int h  = (s >> 4) & 7;
        int ql = s >> 7;
        int l  = i >> 2, p = i & 3;
        float logit = oa_s[ql][256 + h * 16 + i];
        float m = logit;
#pragma unroll
        for (int off = 1; off < 16; off <<= 1) m = fmaxf(m, __shfl_xor(m, off, 64));
        float e = __expf(logit - m);
        float sum = e;
#pragma unroll
        for (int off = 1; off < 16; off <<= 1) sum += __shfl_xor(sum, off, 64);
        float a = e / sum;

        int Wl = HWs[l];
        float fW = (float)Wl;
        float rx = ref_s[ql][l * 2], ry = ref_s[ql][l * 2 + 1];
        float offx = oa_s[ql][h * 32 + l * 8 + p * 2];
        float offy = oa_s[ql][h * 32 + l * 8 + p * 2 + 1];
        float x = rx * fW + offx - 0.5f;
        float y = ry * fW + offy - 0.5f;
        float xf = floorf(x), yf = floorf(y);
        float fx = x - xf, fy = y - yf;
        int x0 = (int)xf, y0 = (int)yf;
        int x1 = x0 + 1, y1 = y0 + 1;
        float wx0 = (x0 >= 0 && x0 < Wl) ? (1.f - fx) : 0.f;
        float wx1 = (x1 >= 0 && x1 < Wl) ? fx : 0.f;
        float wy0 = (y0 >= 0 && y0 < Wl) ? (1.f - fy) : 0.f;
        float wy1 = (y1 >= 0 && y1 < Wl) ? fy : 0.f;
        int x0c = min(max(x0, 0), Wl - 1), x1c = min(max(x1, 0), Wl - 1);
        int y0c = min(max(y0, 0), Wl - 1), y1c = min(max(y1, 0), Wl - 1);
        int r0 = starts[l] + y0c * Wl, r1 = starts[l] + y1c * Wl;
        int ti = i * 33 + ql * 8 + h;
        wtab[ti] = make_float4(wx0 * wy0 * a, wx1 * wy0 * a, wx0 * wy1 * a, wx1 * wy1 * a);
        itab[ti] = make_int4(r0 + x0c, r0 + x1c, r1 + x0c, r1 + x1c);
    }
    __syncthreads();

    // phase 4: gather + weighted accumulate, 4 channels per thread
    const int dg = tid & 7, h = (tid >> 3) & 7, ql = tid >> 6;
    const int q = q0 + ql;
    const int b = q / NQ;
    const char* base = (const char*)v_buf + (size_t)b * NV * 512;
    const unsigned hd8 = (unsigned)h * 64 + (unsigned)dg * 8;
    const int tbase = ql * 8 + h;

    float a0 = 0.f, a1 = 0.f, a2 = 0.f, a3 = 0.f;
#pragma unroll
    for (int lp = 0; lp < 16; lp++) {
        float4 wv = wtab[lp * 33 + tbase];
        int4   ix = itab[lp * 33 + tbase];
        uint2 s0 = *(const uint2*)(base + (((unsigned)ix.x << 9) + hd8));
        uint2 s1 = *(const uint2*)(base + (((unsigned)ix.y << 9) + hd8));
        uint2 s2 = *(const uint2*)(base + (((unsigned)ix.z << 9) + hd8));
        uint2 s3 = *(const uint2*)(base + (((unsigned)ix.w << 9) + hd8));
        a0 += wv.x * bf2f_lo(s0.x); a1 += wv.x * bf2f_hi(s0.x);
        a2 += wv.x * bf2f_lo(s0.y); a3 += wv.x * bf2f_hi(s0.y);
        a0 += wv.y * bf2f_lo(s1.x); a1 += wv.y * bf2f_hi(s1.x);
        a2 += wv.y * bf2f_lo(s1.y); a3 += wv.y * bf2f_hi(s1.y);
        a0 += wv.z * bf2f_lo(s2.x); a1 += wv.z * bf2f_hi(s2.x);
        a2 += wv.z * bf2f_lo(s2.y); a3 += wv.z * bf2f_hi(s2.y);
        a0 += wv.w * bf2f_lo(s3.x); a1 += wv.w * bf2f_hi(s3.x);
        a2 += wv.w * bf2f_lo(s3.y); a3 += wv.w * bf2f_hi(s3.y);
    }
    unsigned o0 = (unsigned)f2bf(a0) | ((unsigned)f2bf(a1) << 16);
    unsigned o1 = (unsigned)f2bf(a2) | ((unsigned)f2bf(a3) << 16);
    uint2 o = {o0, o1};
    *(uint2*)(t_out + (size_t)q * 256 + h * 32 + dg * 4) = o;
}

extern "C" void kernel_launch(void* const* d_in, const int* in_sizes, int n_in,
                              void* d_out, int out_size, void* d_ws, size_t ws_size,
                              hipStream_t stream) {
    const float* query  = (const float*)d_in[0];
    const float* value  = (const float*)d_in[1];
    const float* refpts = (const float*)d_in[2];
    // d_in[3] = spatial_shapes (int32) — fixed {100,50,25,13}^2, hard-coded.
    const float* W_off  = (const float*)d_in[4];
    const float* b_off  = (const float*)d_in[5];
    const float* W_attn = (const float*)d_in[6];
    const float* b_attn = (const float*)d_in[7];
    const float* W_val  = (const float*)d_in[8];
    const float* b_val  = (const float*)d_in[9];
    const float* W_out  = (const float*)d_in[10];
    const float* b_out  = (const float*)d_in[11];

    char* wsp = (char*)d_ws;
    size_t o = 0;
    auto carve = [&](size_t bytes) -> void* {
        void* p = wsp + o; o += (bytes + 255) & ~(size_t)255; return p;
    };
    unsigned short* Wt_val = (unsigned short*)carve(256 * 256 * 2);
    unsigned short* Wt_out = (unsigned short*)carve(256 * 256 * 2);
    unsigned short* Wt_qa  = (unsigned short*)carve(384 * 256 * 2);
    float*          b_qa   = (float*)carve(384 * 4);
    unsigned short* v_buf  = (unsigned short*)carve((size_t)BS * NV * EMBED * 2);
    float*          oa_buf = (float*)carve((size_t)BS * NQ * 384 * 4);
    unsigned short* t_buf  = (unsigned short*)carve((size_t)BS * NQ * EMBED * 2);

    msda_prep_k<<<896, 256, 0, stream>>>(W_val, W_out, W_off, W_attn,
                                         b_off, b_attn, Wt_val, Wt_out, Wt_qa, b_qa);

    // merged: 832 value-GEMM blocks + 750 qa-GEMM blocks; LDS only for EPI0 bounce
    msda_gemm_vq_k<<<832 + 750, 256, 128 * 136 * 2, stream>>>(value, query, Wt_val, Wt_qa,
                                                              b_val, b_qa, v_buf, oa_buf);
    // sampler reads oa_buf + v_buf, writes t_buf
    msda_sampler_k<<<(BS * NQ) / 4, 256, 0, stream>>>(refpts, oa_buf, v_buf, t_buf);
    // out GEMM: 250 m-tiles x 2 n-tiles, barrier-free, zero LDS
    msda_gemm_out_k<<<500, 256, 0, stream>>>(t_buf, Wt_out, b_out, (float*)d_out);
}

// Round 4
// 196.057 us; speedup vs baseline: 1.2603x; 1.2603x over previous
//
#include <hip/hip_runtime.h>
#include <hip/hip_bf16.h>

#define EMBED 256
#define NH 8
#define NL 4
#define NP 4
#define HD 32
#define BS 4
#define NQ 4000
#define NV 13294

using f32x4   = __attribute__((ext_vector_type(4))) float;
using bf16x8  = __attribute__((ext_vector_type(8))) short;

__device__ __forceinline__ float bf2f_lo(unsigned u) {
    union { unsigned u; float f; } x; x.u = u << 16; return x.f;
}
__device__ __forceinline__ float bf2f_hi(unsigned u) {
    union { unsigned u; float f; } x; x.u = u & 0xffff0000u; return x.f;
}
__device__ __forceinline__ unsigned short f2bf(float f) {
    union { float f; unsigned u; } x; x.f = f;
    unsigned u = x.u;
    return (unsigned short)((u + 0x7fffu + ((u >> 16) & 1u)) >> 16);
}
// packed f32->bf16 RNE, 2 elems/instr (no builtin on gfx950; inline asm per guide)
__device__ __forceinline__ unsigned cvtpk(float lo, float hi) {
    unsigned r;
    asm("v_cvt_pk_bf16_f32 %0, %1, %2" : "=v"(r) : "v"(lo), "v"(hi));
    return r;
}

// async 16B/lane global->LDS DMA. LDS dest wave-uniform base; lane i at base+i*16.
__device__ __forceinline__ void async16(const void* g, void* l) {
    __builtin_amdgcn_global_load_lds(
        (const __attribute__((address_space(1))) void*)g,
        (__attribute__((address_space(3))) void*)l, 16, 0, 0);
}

template<int N> __device__ __forceinline__ void wait_vmcnt() {
    if constexpr (N == 0)      asm volatile("s_waitcnt vmcnt(0)" ::: "memory");
    else if constexpr (N == 3) asm volatile("s_waitcnt vmcnt(3)" ::: "memory");
    else if constexpr (N == 4) asm volatile("s_waitcnt vmcnt(4)" ::: "memory");
}

// ---------- prep: weight transposes + bias concat only ----------
__global__ __launch_bounds__(256) void msda_prep_k(
    const float* __restrict__ W_val, const float* __restrict__ W_out,
    const float* __restrict__ W_off, const float* __restrict__ W_attn,
    const float* __restrict__ b_off, const float* __restrict__ b_attn,
    unsigned short* __restrict__ Wt_val, unsigned short* __restrict__ Wt_out,
    unsigned short* __restrict__ Wt_qa, float* __restrict__ b_qa)
{
    int i = blockIdx.x * 256 + threadIdx.x;      // 896 blocks -> 229,376 elems
    if (i < 384) b_qa[i] = (i < 256) ? b_off[i] : b_attn[i - 256];
    if (i < 65536) {
        int r = i >> 8, c = i & 255;
        Wt_val[c * 256 + r] = f2bf(W_val[i]);
    } else if (i < 131072) {
        int j = i - 65536, r = j >> 8, c = j & 255;
        Wt_out[c * 256 + r] = f2bf(W_out[j]);
    } else if (i < 229376) {
        int j = i - 131072;              // j = n*256 + k, n in [0,384)
        int n = j >> 8, k = j & 255;
        float v = (n < 256) ? W_off[k * 256 + n] : W_attn[k * 128 + (n - 256)];
        Wt_qa[j] = f2bf(v);
    }
}

// ---------- GEMM body: triple-buffered LDS, counted-vmcnt pipeline (T3+T4) ----------
// TM=64 tile x 128 N-span; 4 waves, wave w owns N-cols w*32..w*32+31 (NI=2).
// ALL K-loop vmem = global_load_lds DMA => exact per-wave vmcnt counting.
//   depth 2: chunks c, c+1 in flight; per step: wait vmcnt(DPW) [my chunk-c DMAs
//   done] -> s_barrier [all waves'] -> issue chunk c+2 -> compute chunk c.
// A staged as-is (fp32 when ABF16=0, converted on read via v_cvt_pk_bf16_f32).
// XOR-swizzle on BOTH DMA source col and ds_read col (rule 21):
//   fp32 rows (128B): unit p holds global unit p^(row&7) -> 2-way conflict (free).
//   bf16 rows (64B):  unit p holds global unit p^(row&3) -> 4-way.
// EPI 0: bf16 [M][N] via LDS bounce (coalesced 64B row stores). EPI 1: fp32 direct.
template<int TM, int EPI, bool ABF16>
__device__ __forceinline__ void gemm_body(
    char* lds,
    const void* __restrict__ Ap,
    const unsigned short* __restrict__ Bt,
    const float* __restrict__ bias,
    void* __restrict__ out,
    int M, int N, int mblk, int nblk)
{
    constexpr int K = 256, C = 8;
    constexpr int NI = 2;
    constexpr int ABYTES = TM * 32 * (ABF16 ? 2 : 4);   // 4096 | 8192
    constexpr int BBYTES = 128 * 32 * 2;                // 8192
    constexpr int BUFB = ABYTES + BBYTES;               // per pipeline buffer
    constexpr int AIPW = ABYTES / 4096;                 // A DMA instrs / wave / chunk
    constexpr int DPW  = AIPW + 2;                      // total DMA / wave / chunk

    const int m0 = mblk * TM, n0 = nblk * 128;
    const int tid  = threadIdx.x;
    const int w    = tid >> 6;
    const int lane = tid & 63;
    const int quad = lane >> 4;
    const int l16  = lane & 15;
    const int wn   = w * 32;

    // ---- per-lane DMA source pointers (swizzled global col) ----
    const char* agp[AIPW];
#pragma unroll
    for (int j = 0; j < AIPW; j++) {
        int ai = w * AIPW + j;
        if constexpr (ABF16) {
            int row  = ai * 16 + (lane >> 2);            // 16 rows x 64B per instr
            int rowg = min(m0 + row, M - 1);
            int scol = (lane & 3) ^ ((lane >> 2) & 3);
            agp[j] = (const char*)Ap + (size_t)rowg * 512 + scol * 16;
        } else {
            int row  = ai * 8 + (lane >> 3);             // 8 rows x 128B per instr
            int rowg = min(m0 + row, M - 1);
            int scol = (lane & 7) ^ (lane >> 3);
            agp[j] = (const char*)Ap + (size_t)rowg * 1024 + scol * 16;
        }
    }
    const char* bgp[2];
#pragma unroll
    for (int j = 0; j < 2; j++) {
        int bi   = w * 2 + j;
        int row  = bi * 16 + (lane >> 2);
        int scol = (lane & 3) ^ ((lane >> 2) & 3);
        bgp[j] = (const char*)Bt + (size_t)(n0 + row) * 512 + scol * 16;
    }

    auto issue = [&](int c, int kb) {
        char* aL = lds + kb * BUFB;
        char* bL = aL + ABYTES;
        const int ko = c * (ABF16 ? 64 : 128);
#pragma unroll
        for (int j = 0; j < AIPW; j++)
            async16(agp[j] + ko, aL + (w * AIPW + j) * 1024);
#pragma unroll
        for (int j = 0; j < 2; j++)
            async16(bgp[j] + c * 64, bL + (w * 2 + j) * 1024);
    };

    f32x4 acc[4][NI];
#pragma unroll
    for (int a = 0; a < 4; a++)
#pragma unroll
        for (int b = 0; b < NI; b++) acc[a][b] = (f32x4){0.f, 0.f, 0.f, 0.f};

    issue(0, 0);
    issue(1, 1);
#pragma unroll
    for (int c = 0; c < C; c++) {
        if (c + 1 < C) wait_vmcnt<DPW>(); else wait_vmcnt<0>();
        __builtin_amdgcn_s_barrier();            // all waves' chunk-c DMAs landed
        __builtin_amdgcn_sched_barrier(0);       // pin ds_reads below the barrier
        if (c + 2 < C) issue(c + 2, (c + 2) % 3);

        const char* aL = lds + (c % 3) * BUFB;
        const char* bL = aL + ABYTES;
        bf16x8 af[4], bfr[NI];
#pragma unroll
        for (int mi = 0; mi < 4; mi++) {
            int row = mi * 16 + l16;
            if constexpr (ABF16) {
                af[mi] = *(const bf16x8*)(aL + row * 64 + ((quad ^ (row & 3)) * 16));
            } else {
                f32x4 lo = *(const f32x4*)(aL + row * 128 + (((2 * quad)     ^ (row & 7)) * 16));
                f32x4 hi = *(const f32x4*)(aL + row * 128 + (((2 * quad + 1) ^ (row & 7)) * 16));
                union { unsigned u[4]; bf16x8 v; } t;
                t.u[0] = cvtpk(lo[0], lo[1]); t.u[1] = cvtpk(lo[2], lo[3]);
                t.u[2] = cvtpk(hi[0], hi[1]); t.u[3] = cvtpk(hi[2], hi[3]);
                af[mi] = t.v;
            }
        }
#pragma unroll
        for (int ni = 0; ni < NI; ni++) {
            int row = wn + ni * 16 + l16;
            bfr[ni] = *(const bf16x8*)(bL + row * 64 + ((quad ^ (row & 3)) * 16));
        }
#pragma unroll
        for (int mi = 0; mi < 4; mi++)
#pragma unroll
            for (int ni = 0; ni < NI; ni++)
                acc[mi][ni] = __builtin_amdgcn_mfma_f32_16x16x32_bf16(af[mi], bfr[ni], acc[mi][ni], 0, 0, 0);
    }

    if constexpr (EPI == 0) {
        __syncthreads();                          // cs overlaps pipeline buffers
        unsigned short* cs = (unsigned short*)lds;   // [64][136] bf16
#pragma unroll
        for (int ni = 0; ni < NI; ni++) {
            int cl = wn + ni * 16 + l16;
            float bvv = bias[n0 + cl];
#pragma unroll
            for (int mi = 0; mi < 4; mi++)
#pragma unroll
                for (int r = 0; r < 4; r++) {
                    int ml = mi * 16 + quad * 4 + r;
                    cs[ml * 136 + cl] = f2bf(acc[mi][ni][r] + bvv);
                }
        }
        __syncthreads();
        const int row = tid >> 2, seg = tid & 3;     // 64 rows x 4 x 64B segs
        const int m = m0 + row;
        if (m < M) {
            const uint4* s = (const uint4*)&cs[row * 136 + seg * 32];
            uint4* d = (uint4*)((unsigned short*)out + (size_t)m * N + n0 + seg * 32);
#pragma unroll
            for (int j = 0; j < 4; j++) d[j] = s[j];
        }
    } else {
#pragma unroll
        for (int ni = 0; ni < NI; ni++) {
            int cc = n0 + wn + ni * 16 + l16;
            float bvv = bias[cc];
#pragma unroll
            for (int mi = 0; mi < 4; mi++)
#pragma unroll
                for (int r = 0; r < 4; r++) {
                    int m = m0 + mi * 16 + quad * 4 + r;
                    if (m >= M) continue;
                    ((float*)out)[(size_t)m * N + cc] = acc[mi][ni][r] + bvv;
                }
        }
    }
}

// ---------- merged value-GEMM + qa-GEMM ----------
// value: 831 m-tiles x 2 n = 1662 blocks (EPI0, A fp32)
// qa:    250 m-tiles x 3 n =  750 blocks (EPI1, A fp32)
__global__ __launch_bounds__(256) void msda_gemm_vq_k(
    const float* __restrict__ value, const float* __restrict__ query,
    const unsigned short* __restrict__ Wt_val, const unsigned short* __restrict__ Wt_qa,
    const float* __restrict__ b_val, const float* __restrict__ b_qa,
    unsigned short* __restrict__ v_buf, float* __restrict__ oa_buf)
{
    extern __shared__ char lds[];
    const int bx = blockIdx.x;
    if (bx < 1662) {
        gemm_body<64, 0, false>(lds, value, Wt_val, b_val, v_buf,
                                BS * NV, 256, bx >> 1, bx & 1);
    } else {
        const int j = bx - 1662;
        const int mb = j / 3;
        gemm_body<64, 1, false>(lds, query, Wt_qa, b_qa, oa_buf,
                                BS * NQ, 384, mb, j - mb * 3);
    }
}

// ---------- out GEMM (after sampler): A bf16 via DMA ----------
__global__ __launch_bounds__(256) void msda_gemm_out_k(
    const unsigned short* __restrict__ t_buf,
    const unsigned short* __restrict__ Wt_out,
    const float* __restrict__ b_out,
    float* __restrict__ out)
{
    extern __shared__ char lds[];
    const int bx = blockIdx.x;
    gemm_body<64, 1, true>(lds, t_buf, Wt_out, b_out, out,
                           BS * NQ, 256, bx >> 1, bx & 1);
}

// ---------- sampler: 4 queries/block, wave = 1 query, thread = (h, 4-chan grp) ----------
__global__ __launch_bounds__(256) void msda_sampler_k(
    const float* __restrict__ refpts,            // (BS*NQ, 8) fp32
    const float* __restrict__ oa_buf,            // (BS*NQ, 384) fp32: off[256] | attn[128]
    const unsigned short* __restrict__ v_buf,    // (BS*NV, 256) bf16 row-major
    unsigned short* __restrict__ t_out)          // (BS*NQ, 256) bf16
{
    __shared__ float  oa_s[4][384];
    __shared__ float  ref_s[4][8];
    __shared__ float4 wtab[528];                 // idx = i*33 + ql*8 + h (stride-33 pad)
    __shared__ int4   itab[528];

    const int tid = threadIdx.x;
    const int q0  = blockIdx.x * 4;

    // phase 1: cooperative loads
    {
        const float4* src = (const float4*)(oa_buf + (size_t)q0 * 384);
        float4* dst = (float4*)&oa_s[0][0];
        dst[tid] = src[tid];
        if (tid < 128) dst[256 + tid] = src[256 + tid];
        if (tid < 32) ((float*)ref_s)[tid] = refpts[q0 * 8 + tid];
    }
    __syncthreads();

    // phase 2+3 fused: shuffle softmax (16 lanes = one (q,h) group) + tables
    const int HWs[4]    = {100, 50, 25, 13};
    const int starts[4] = {0, 10000, 12500, 13125};
#pragma unroll
    for (int it = 0; it < 2; it++) {
        int s  = tid + it * 256;                 // 0..511
        int i  = s & 15;                         // l*4+p
        int h  = (s >> 4) & 7;
        int ql = s >> 7;
        int l  = i >> 2, p = i & 3;
        float logit = oa_s[ql][256 + h * 16 + i];
        float m = logit;
#pragma unroll
        for (int off = 1; off < 16; off <<= 1) m = fmaxf(m, __shfl_xor(m, off, 64));
        float e = __expf(logit - m);
        float sum = e;
#pragma unroll
        for (int off = 1; off < 16; off <<= 1) sum += __shfl_xor(sum, off, 64);
        float a = e / sum;

        int Wl = HWs[l];
        float fW = (float)Wl;
        float rx = ref_s[ql][l * 2], ry = ref_s[ql][l * 2 + 1];
        float offx = oa_s[ql][h * 32 + l * 8 + p * 2];
        float offy = oa_s[ql][h * 32 + l * 8 + p * 2 + 1];
        float x = rx * fW + offx - 0.5f;
        float y = ry * fW + offy - 0.5f;
        float xf = floorf(x), yf = floorf(y);
        float fx = x - xf, fy = y - yf;
        int x0 = (int)xf, y0 = (int)yf;
        int x1 = x0 + 1, y1 = y0 + 1;
        float wx0 = (x0 >= 0 && x0 < Wl) ? (1.f - fx) : 0.f;
        float wx1 = (x1 >= 0 && x1 < Wl) ? fx : 0.f;
        float wy0 = (y0 >= 0 && y0 < Wl) ? (1.f - fy) : 0.f;
        float wy1 = (y1 >= 0 && y1 < Wl) ? fy : 0.f;
        int x0c = min(max(x0, 0), Wl - 1), x1c = min(max(x1, 0), Wl - 1);
        int y0c = min(max(y0, 0), Wl - 1), y1c = min(max(y1, 0), Wl - 1);
        int r0 = starts[l] + y0c * Wl, r1 = starts[l] + y1c * Wl;
        int ti = i * 33 + ql * 8 + h;
        wtab[ti] = make_float4(wx0 * wy0 * a, wx1 * wy0 * a, wx0 * wy1 * a, wx1 * wy1 * a);
        itab[ti] = make_int4(r0 + x0c, r0 + x1c, r1 + x0c, r1 + x1c);
    }
    __syncthreads();

    // phase 4: gather + weighted accumulate, 4 channels per thread
    const int dg = tid & 7, h = (tid >> 3) & 7, ql = tid >> 6;
    const int q = q0 + ql;
    const int b = q / NQ;
    const char* base = (const char*)v_buf + (size_t)b * NV * 512;
    const unsigned hd8 = (unsigned)h * 64 + (unsigned)dg * 8;
    const int tbase = ql * 8 + h;

    float a0 = 0.f, a1 = 0.f, a2 = 0.f, a3 = 0.f;
#pragma unroll
    for (int lp = 0; lp < 16; lp++) {
        float4 wv = wtab[lp * 33 + tbase];
        int4   ix = itab[lp * 33 + tbase];
        uint2 s0 = *(const uint2*)(base + (((unsigned)ix.x << 9) + hd8));
        uint2 s1 = *(const uint2*)(base + (((unsigned)ix.y << 9) + hd8));
        uint2 s2 = *(const uint2*)(base + (((unsigned)ix.z << 9) + hd8));
        uint2 s3 = *(const uint2*)(base + (((unsigned)ix.w << 9) + hd8));
        a0 += wv.x * bf2f_lo(s0.x); a1 += wv.x * bf2f_hi(s0.x);
        a2 += wv.x * bf2f_lo(s0.y); a3 += wv.x * bf2f_hi(s0.y);
        a0 += wv.y * bf2f_lo(s1.x); a1 += wv.y * bf2f_hi(s1.x);
        a2 += wv.y * bf2f_lo(s1.y); a3 += wv.y * bf2f_hi(s1.y);
        a0 += wv.z * bf2f_lo(s2.x); a1 += wv.z * bf2f_hi(s2.x);
        a2 += wv.z * bf2f_lo(s2.y); a3 += wv.z * bf2f_hi(s2.y);
        a0 += wv.w * bf2f_lo(s3.x); a1 += wv.w * bf2f_hi(s3.x);
        a2 += wv.w * bf2f_lo(s3.y); a3 += wv.w * bf2f_hi(s3.y);
    }
    unsigned o0 = (unsigned)f2bf(a0) | ((unsigned)f2bf(a1) << 16);
    unsigned o1 = (unsigned)f2bf(a2) | ((unsigned)f2bf(a3) << 16);
    uint2 o = {o0, o1};
    *(uint2*)(t_out + (size_t)q * 256 + h * 32 + dg * 4) = o;
}

extern "C" void kernel_launch(void* const* d_in, const int* in_sizes, int n_in,
                              void* d_out, int out_size, void* d_ws, size_t ws_size,
                              hipStream_t stream) {
    const float* query  = (const float*)d_in[0];
    const float* value  = (const float*)d_in[1];
    const float* refpts = (const float*)d_in[2];
    // d_in[3] = spatial_shapes (int32) — fixed {100,50,25,13}^2, hard-coded.
    const float* W_off  = (const float*)d_in[4];
    const float* b_off  = (const float*)d_in[5];
    const float* W_attn = (const float*)d_in[6];
    const float* b_attn = (const float*)d_in[7];
    const float* W_val  = (const float*)d_in[8];
    const float* b_val  = (const float*)d_in[9];
    const float* W_out  = (const float*)d_in[10];
    const float* b_out  = (const float*)d_in[11];

    char* wsp = (char*)d_ws;
    size_t o = 0;
    auto carve = [&](size_t bytes) -> void* {
        void* p = wsp + o; o += (bytes + 255) & ~(size_t)255; return p;
    };
    unsigned short* Wt_val = (unsigned short*)carve(256 * 256 * 2);
    unsigned short* Wt_out = (unsigned short*)carve(256 * 256 * 2);
    unsigned short* Wt_qa  = (unsigned short*)carve(384 * 256 * 2);
    float*          b_qa   = (float*)carve(384 * 4);
    unsigned short* v_buf  = (unsigned short*)carve((size_t)BS * NV * EMBED * 2);
    float*          oa_buf = (float*)carve((size_t)BS * NQ * 384 * 4);
    unsigned short* t_buf  = (unsigned short*)carve((size_t)BS * NQ * EMBED * 2);

    msda_prep_k<<<896, 256, 0, stream>>>(W_val, W_out, W_off, W_attn,
                                         b_off, b_attn, Wt_val, Wt_out, Wt_qa, b_qa);

    // merged: 1662 value blocks + 750 qa blocks; 3x16KB pipeline LDS
    msda_gemm_vq_k<<<1662 + 750, 256, 49152, stream>>>(value, query, Wt_val, Wt_qa,
                                                       b_val, b_qa, v_buf, oa_buf);
    // sampler reads oa_buf + v_buf, writes t_buf
    msda_sampler_k<<<(BS * NQ) / 4, 256, 0, stream>>>(refpts, oa_buf, v_buf, t_buf);
    // out GEMM: 250 m-tiles x 2 n-tiles, 3x12KB pipeline LDS
    msda_gemm_out_k<<<500, 256, 36864, stream>>>(t_buf, Wt_out, b_out, (float*)d_out);
}

// Round 5
// 195.979 us; speedup vs baseline: 1.2608x; 1.0004x over previous
//
#include <hip/hip_runtime.h>
#include <hip/hip_bf16.h>

#define EMBED 256
#define NH 8
#define NL 4
#define NP 4
#define HD 32
#define BS 4
#define NQ 4000
#define NV 13294

using f32x4   = __attribute__((ext_vector_type(4))) float;
using bf16x8  = __attribute__((ext_vector_type(8))) short;

__device__ __forceinline__ float bf2f_lo(unsigned u) {
    union { unsigned u; float f; } x; x.u = u << 16; return x.f;
}
__device__ __forceinline__ float bf2f_hi(unsigned u) {
    union { unsigned u; float f; } x; x.u = u & 0xffff0000u; return x.f;
}
__device__ __forceinline__ unsigned short f2bf(float f) {
    union { float f; unsigned u; } x; x.f = f;
    unsigned u = x.u;
    return (unsigned short)((u + 0x7fffu + ((u >> 16) & 1u)) >> 16);
}
// packed f32->bf16 RNE, 2 elems/instr
__device__ __forceinline__ unsigned cvtpk(float lo, float hi) {
    unsigned r;
    asm("v_cvt_pk_bf16_f32 %0, %1, %2" : "=v"(r) : "v"(lo), "v"(hi));
    return r;
}

// async 16B/lane global->LDS DMA. LDS dest wave-uniform base; lane i at base+i*16.
__device__ __forceinline__ void async16(const void* g, void* l) {
    __builtin_amdgcn_global_load_lds(
        (const __attribute__((address_space(1))) void*)g,
        (__attribute__((address_space(3))) void*)l, 16, 0, 0);
}

template<int N> __device__ __forceinline__ void wait_vmcnt() {
    if constexpr (N == 0)      asm volatile("s_waitcnt vmcnt(0)" ::: "memory");
    else if constexpr (N == 3) asm volatile("s_waitcnt vmcnt(3)" ::: "memory");
    else if constexpr (N == 4) asm volatile("s_waitcnt vmcnt(4)" ::: "memory");
}

// ---------- prep: weight transposes + bias concat only ----------
__global__ __launch_bounds__(256) void msda_prep_k(
    const float* __restrict__ W_val, const float* __restrict__ W_out,
    const float* __restrict__ W_off, const float* __restrict__ W_attn,
    const float* __restrict__ b_off, const float* __restrict__ b_attn,
    unsigned short* __restrict__ Wt_val, unsigned short* __restrict__ Wt_out,
    unsigned short* __restrict__ Wt_qa, float* __restrict__ b_qa)
{
    int i = blockIdx.x * 256 + threadIdx.x;      // 896 blocks -> 229,376 elems
    if (i < 384) b_qa[i] = (i < 256) ? b_off[i] : b_attn[i - 256];
    if (i < 65536) {
        int r = i >> 8, c = i & 255;
        Wt_val[c * 256 + r] = f2bf(W_val[i]);
    } else if (i < 131072) {
        int j = i - 65536, r = j >> 8, c = j & 255;
        Wt_out[c * 256 + r] = f2bf(W_out[j]);
    } else if (i < 229376) {
        int j = i - 131072;              // j = n*256 + k, n in [0,384)
        int n = j >> 8, k = j & 255;
        float v = (n < 256) ? W_off[k * 256 + n] : W_attn[k * 128 + (n - 256)];
        Wt_qa[j] = f2bf(v);
    }
}

// ---------- GEMM body: reg-staged bf16 A + DMA B, triple-buffered counted-vmcnt ----------
// TM=64 x TN=128, 4 waves, wave w owns N-cols w*32..+31 (NI=2).
// A staging (T14): global fp32 -> regs (issued 1 iter early, 2 parity reg-sets) ->
//   cvt_pk bf16 -> ds_write_b128 into buf (c+1)%3.  A in LDS is bf16 [64][32]:
//   halves buffer (12KB) vs fp32 staging -> 36KB total -> 4 blocks/CU, and cuts
//   fragment LDS reads 160->96 B/lane/chunk with no cvt on the MFMA path.
// B staging: global_load_lds DMA (2 instrs/wave/chunk), linear [128][32] bf16.
// vmcnt discipline (in-order vmem retirement makes counts safe):
//   iter c issues [L(c+2), B(c+2)]; manual wait at top of iter c needs B(c) done:
//   L(c) was force-completed by writeA(c)'s register dependency in iter c-1, so
//   outstanding ⊆ {B(c), L(c+1), B(c+1)}; in-order retire => vmcnt(LOPS+2) drains
//   B(c).  writeA(c+1)'s own wait is compiler-inserted (exact, no over-drain).
//   sched_barrier(0) at each iter top fences cross-iteration reordering.
// EPI 0: bf16 out in [b][h][pix][32ch] layout via LDS bounce (v_buf for sampler).
// EPI 1: fp32 row-major [M][N] direct.
template<int EPI, bool ABF16>
__device__ __forceinline__ void gemm_body(
    char* lds,
    const void* __restrict__ Ap,
    const unsigned short* __restrict__ Bt,
    const float* __restrict__ bias,
    void* __restrict__ out,
    int M, int N, int mblk, int nblk)
{
    constexpr int K = 256, C = 8;
    constexpr int NI = 2;
    constexpr int ABYTES = 64 * 32 * 2;          // 4096 (A always bf16 in LDS)
    constexpr int BBYTES = 128 * 32 * 2;         // 8192
    constexpr int BUFB   = ABYTES + BBYTES;      // 12288
    constexpr int LOPS   = ABF16 ? 1 : 2;        // A global loads / lane / chunk

    const int m0 = mblk * 64, n0 = nblk * 128;
    const int tid  = threadIdx.x;
    const int w    = tid >> 6;
    const int lane = tid & 63;
    const int quad = lane >> 4;
    const int l16  = lane & 15;
    const int wn   = w * 32;

    // ---- A reg-stage mapping: row = w*16 + lane>>2, k-elems (lane&3)*8..+8 ----
    const int ar  = w * 16 + (lane >> 2);
    const int arg = min(m0 + ar, M - 1);
    const int ak  = (lane & 3) * 8;
    const float*          afp = (const float*)Ap          + (size_t)arg * K + ak;
    const unsigned short* abp = (const unsigned short*)Ap + (size_t)arg * K + ak;

    // ---- B DMA: 2 instrs/wave/chunk, 16 rows x 64B each, linear dest ----
    const int brseg = lane >> 2, bcb = (lane & 3) * 16;
    const char* bgp0 = (const char*)(Bt + (size_t)(n0 + (2 * w) * 16 + brseg) * K) + bcb;
    const char* bgp1 = (const char*)(Bt + (size_t)(n0 + (2 * w + 1) * 16 + brseg) * K) + bcb;

    auto issueB = [&](int c, int kb) {
        char* bL = lds + kb * BUFB + ABYTES;
        async16(bgp0 + c * 64, bL + (2 * w) * 1024);
        async16(bgp1 + c * 64, bL + (2 * w + 1) * 1024);
    };

    float4 aLoR[2], aHiR[2];                     // parity reg-sets (unroll folds idx)
    bf16x8 aRegR[2];
    auto loadA = [&](int c) {
        const int p = c & 1;
        if constexpr (ABF16) {
            aRegR[p] = *(const bf16x8*)(abp + c * 32);
        } else {
            aLoR[p] = *(const float4*)(afp + c * 32);
            aHiR[p] = *(const float4*)(afp + c * 32 + 4);
        }
    };
    auto writeA = [&](int c) {
        const int p = c & 1;
        unsigned short* dst = (unsigned short*)(lds + (c % 3) * BUFB) + ar * 32 + ak;
        if constexpr (ABF16) {
            *(bf16x8*)dst = aRegR[p];
        } else {
            union { unsigned u[4]; bf16x8 v; } t;
            t.u[0] = cvtpk(aLoR[p].x, aLoR[p].y); t.u[1] = cvtpk(aLoR[p].z, aLoR[p].w);
            t.u[2] = cvtpk(aHiR[p].x, aHiR[p].y); t.u[3] = cvtpk(aHiR[p].z, aHiR[p].w);
            *(bf16x8*)dst = t.v;
        }
    };

    f32x4 acc[4][NI];
#pragma unroll
    for (int a = 0; a < 4; a++)
#pragma unroll
        for (int b = 0; b < NI; b++) acc[a][b] = (f32x4){0.f, 0.f, 0.f, 0.f};

    // prologue: L(0), B(0), L(1), B(1); writeA(0) (compiler waits L(0) regs)
    loadA(0); issueB(0, 0); loadA(1); issueB(1, 1);
    writeA(0);

#pragma unroll
    for (int c = 0; c < C; c++) {
        if (c < C - 1) wait_vmcnt<LOPS + 2>(); else wait_vmcnt<0>();
        asm volatile("s_waitcnt lgkmcnt(0)" ::: "memory");   // my A ds_writes visible
        __builtin_amdgcn_s_barrier();                        // buf c%3 fully valid
        __builtin_amdgcn_sched_barrier(0);                   // iteration fence
        if (c + 2 < C) { loadA(c + 2); issueB(c + 2, (c + 2) % 3); }

        const char* aL = lds + (c % 3) * BUFB;
        const char* bL = aL + ABYTES;
        bf16x8 af[4], bfr[NI];
#pragma unroll
        for (int mi = 0; mi < 4; mi++)
            af[mi] = *(const bf16x8*)(aL + (mi * 16 + l16) * 64 + quad * 16);
#pragma unroll
        for (int ni = 0; ni < NI; ni++)
            bfr[ni] = *(const bf16x8*)(bL + (wn + ni * 16 + l16) * 64 + quad * 16);

        if (c + 1 < C) writeA(c + 1);            // buf (c+1)%3 last read iter c-2: safe

#pragma unroll
        for (int mi = 0; mi < 4; mi++)
#pragma unroll
            for (int ni = 0; ni < NI; ni++)
                acc[mi][ni] = __builtin_amdgcn_mfma_f32_16x16x32_bf16(af[mi], bfr[ni], acc[mi][ni], 0, 0, 0);
    }

    if constexpr (EPI == 0) {
        // bounce -> v_buf in [b][h][pix][32ch] bf16 layout (sampler-friendly:
        // x-adjacent bilinear corners 64B apart -> share cachelines)
        __syncthreads();                          // cs overlaps pipeline buffers
        unsigned short* cs = (unsigned short*)lds;   // [64][136]
#pragma unroll
        for (int ni = 0; ni < NI; ni++) {
            int cl = wn + ni * 16 + l16;
            float bvv = bias[n0 + cl];
#pragma unroll
            for (int mi = 0; mi < 4; mi++)
#pragma unroll
                for (int r = 0; r < 4; r++) {
                    int ml = mi * 16 + quad * 4 + r;
                    cs[ml * 136 + cl] = f2bf(acc[mi][ni][r] + bvv);
                }
        }
        __syncthreads();
        // writer: wave w -> rows w*16..+15; lane = (row 0..15)*4 + 16B-chunk jj;
        // per seg-iter a wave stores 16 consecutive pixels x 64B = 1KB contiguous.
        const int rr = w * 16 + (lane >> 2);
        const int jj = lane & 3;
        const int m  = m0 + rr;
        if (m < M) {
            const int b   = m / NV;
            const int pix = m - b * NV;
#pragma unroll
            for (int seg = 0; seg < 4; seg++) {
                const int h = (n0 >> 5) + seg;
                uint4 s = *(const uint4*)&cs[rr * 136 + seg * 32 + jj * 8];
                *(uint4*)((char*)out + (((size_t)b * 8 + h) * NV + pix) * 64 + jj * 16) = s;
            }
        }
    } else {
#pragma unroll
        for (int ni = 0; ni < NI; ni++) {
            int cc = n0 + wn + ni * 16 + l16;
            float bvv = bias[cc];
#pragma unroll
            for (int mi = 0; mi < 4; mi++)
#pragma unroll
                for (int r = 0; r < 4; r++) {
                    int m = m0 + mi * 16 + quad * 4 + r;
                    if (m >= M) continue;
                    ((float*)out)[(size_t)m * N + cc] = acc[mi][ni][r] + bvv;
                }
        }
    }
}

// ---------- merged value-GEMM + qa-GEMM ----------
// value: 831 m-tiles x 2 n = 1662 blocks (EPI0, A fp32)
// qa:    250 m-tiles x 3 n =  750 blocks (EPI1, A fp32)
__global__ __launch_bounds__(256) void msda_gemm_vq_k(
    const float* __restrict__ value, const float* __restrict__ query,
    const unsigned short* __restrict__ Wt_val, const unsigned short* __restrict__ Wt_qa,
    const float* __restrict__ b_val, const float* __restrict__ b_qa,
    unsigned short* __restrict__ v_buf, float* __restrict__ oa_buf)
{
    extern __shared__ char lds[];
    const int bx = blockIdx.x;
    if (bx < 1662) {
        gemm_body<0, false>(lds, value, Wt_val, b_val, v_buf,
                            BS * NV, 256, bx >> 1, bx & 1);
    } else {
        const int j = bx - 1662;
        const int mb = j / 3;
        gemm_body<1, false>(lds, query, Wt_qa, b_qa, oa_buf,
                            BS * NQ, 384, mb, j - mb * 3);
    }
}

// ---------- out GEMM (after sampler): A bf16 reg-staged ----------
__global__ __launch_bounds__(256) void msda_gemm_out_k(
    const unsigned short* __restrict__ t_buf,
    const unsigned short* __restrict__ Wt_out,
    const float* __restrict__ b_out,
    float* __restrict__ out)
{
    extern __shared__ char lds[];
    const int bx = blockIdx.x;
    gemm_body<1, true>(lds, t_buf, Wt_out, b_out, out,
                       BS * NQ, 256, bx >> 1, bx & 1);
}

// ---------- sampler: 4 queries/block, wave = 1 query, thread = (h, 4-chan grp) ----------
// v_buf layout: [b][h][pix][32ch] bf16 (64B per (b,h,pix) row)
__global__ __launch_bounds__(256) void msda_sampler_k(
    const float* __restrict__ refpts,            // (BS*NQ, 8) fp32
    const float* __restrict__ oa_buf,            // (BS*NQ, 384) fp32: off[256] | attn[128]
    const unsigned short* __restrict__ v_buf,    // [BS][NH][NV][32] bf16
    unsigned short* __restrict__ t_out)          // (BS*NQ, 256) bf16
{
    __shared__ float  oa_s[4][384];
    __shared__ float  ref_s[4][8];
    __shared__ float4 wtab[528];                 // idx = i*33 + ql*8 + h (stride-33 pad)
    __shared__ int4   itab[528];

    const int tid = threadIdx.x;
    const int q0  = blockIdx.x * 4;

    // phase 1: cooperative loads
    {
        const float4* src = (const float4*)(oa_buf + (size_t)q0 * 384);
        float4* dst = (float4*)&oa_s[0][0];
        dst[tid] = src[tid];
        if (tid < 128) dst[256 + tid] = src[256 + tid];
        if (tid < 32) ((float*)ref_s)[tid] = refpts[q0 * 8 + tid];
    }
    __syncthreads();

    // phase 2+3 fused: shuffle softmax (16 lanes = one (q,h) group) + tables
    const int HWs[4]    = {100, 50, 25, 13};
    const int starts[4] = {0, 10000, 12500, 13125};
#pragma unroll
    for (int it = 0; it < 2; it++) {
        int s  = tid + it * 256;                 // 0..511
        int i  = s & 15;                         // l*4+p
        int h  = (s >> 4) & 7;
        int ql = s >> 7;
        int l  = i >> 2, p = i & 3;
        float logit = oa_s[ql][256 + h * 16 + i];
        float m = logit;
#pragma unroll
        for (int off = 1; off < 16; off <<= 1) m = fmaxf(m, __shfl_xor(m, off, 64));
        float e = __expf(logit - m);
        float sum = e;
#pragma unroll
        for (int off = 1; off < 16; off <<= 1) sum += __shfl_xor(sum, off, 64);
        float a = e / sum;

        int Wl = HWs[l];
        float fW = (float)Wl;
        float rx = ref_s[ql][l * 2], ry = ref_s[ql][l * 2 + 1];
        float offx = oa_s[ql][h * 32 + l * 8 + p * 2];
        float offy = oa_s[ql][h * 32 + l * 8 + p * 2 + 1];
        float x = rx * fW + offx - 0.5f;
        float y = ry * fW + offy - 0.5f;
        float xf = floorf(x), yf = floorf(y);
        float fx = x - xf, fy = y - yf;
        int x0 = (int)xf, y0 = (int)yf;
        int x1 = x0 + 1, y1 = y0 + 1;
        float wx0 = (x0 >= 0 && x0 < Wl) ? (1.f - fx) : 0.f;
        float wx1 = (x1 >= 0 && x1 < Wl) ? fx : 0.f;
        float wy0 = (y0 >= 0 && y0 < Wl) ? (1.f - fy) : 0.f;
        float wy1 = (y1 >= 0 && y1 < Wl) ? fy : 0.f;
        int x0c = min(max(x0, 0), Wl - 1), x1c = min(max(x1, 0), Wl - 1);
        int y0c = min(max(y0, 0), Wl - 1), y1c = min(max(y1, 0), Wl - 1);
        int r0 = starts[l] + y0c * Wl, r1 = starts[l] + y1c * Wl;
        int ti = i * 33 + ql * 8 + h;
        wtab[ti] = make_float4(wx0 * wy0 * a, wx1 * wy0 * a, wx0 * wy1 * a, wx1 * wy1 * a);
        itab[ti] = make_int4(r0 + x0c, r0 + x1c, r1 + x0c, r1 + x1c);
    }
    __syncthreads();

    // phase 4: gather + weighted accumulate, 4 channels per thread
    const int dg = tid & 7, h = (tid >> 3) & 7, ql = tid >> 6;
    const int q = q0 + ql;
    const int b = q / NQ;
    const char* base = (const char*)v_buf + ((size_t)(b * 8 + h)) * NV * 64 + dg * 8;
    const int tbase = ql * 8 + h;

    float a0 = 0.f, a1 = 0.f, a2 = 0.f, a3 = 0.f;
#pragma unroll
    for (int lp = 0; lp < 16; lp++) {
        float4 wv = wtab[lp * 33 + tbase];
        int4   ix = itab[lp * 33 + tbase];
        uint2 s0 = *(const uint2*)(base + ((unsigned)ix.x << 6));
        uint2 s1 = *(const uint2*)(base + ((unsigned)ix.y << 6));
        uint2 s2 = *(const uint2*)(base + ((unsigned)ix.z << 6));
        uint2 s3 = *(const uint2*)(base + ((unsigned)ix.w << 6));
        a0 += wv.x * bf2f_lo(s0.x); a1 += wv.x * bf2f_hi(s0.x);
        a2 += wv.x * bf2f_lo(s0.y); a3 += wv.x * bf2f_hi(s0.y);
        a0 += wv.y * bf2f_lo(s1.x); a1 += wv.y * bf2f_hi(s1.x);
        a2 += wv.y * bf2f_lo(s1.y); a3 += wv.y * bf2f_hi(s1.y);
        a0 += wv.z * bf2f_lo(s2.x); a1 += wv.z * bf2f_hi(s2.x);
        a2 += wv.z * bf2f_lo(s2.y); a3 += wv.z * bf2f_hi(s2.y);
        a0 += wv.w * bf2f_lo(s3.x); a1 += wv.w * bf2f_hi(s3.x);
        a2 += wv.w * bf2f_lo(s3.y); a3 += wv.w * bf2f_hi(s3.y);
    }
    unsigned o0 = (unsigned)f2bf(a0) | ((unsigned)f2bf(a1) << 16);
    unsigned o1 = (unsigned)f2bf(a2) | ((unsigned)f2bf(a3) << 16);
    uint2 o = {o0, o1};
    *(uint2*)(t_out + (size_t)q * 256 + h * 32 + dg * 4) = o;
}

extern "C" void kernel_launch(void* const* d_in, const int* in_sizes, int n_in,
                              void* d_out, int out_size, void* d_ws, size_t ws_size,
                              hipStream_t stream) {
    const float* query  = (const float*)d_in[0];
    const float* value  = (const float*)d_in[1];
    const float* refpts = (const float*)d_in[2];
    // d_in[3] = spatial_shapes (int32) — fixed {100,50,25,13}^2, hard-coded.
    const float* W_off  = (const float*)d_in[4];
    const float* b_off  = (const float*)d_in[5];
    const float* W_attn = (const float*)d_in[6];
    const float* b_attn = (const float*)d_in[7];
    const float* W_val  = (const float*)d_in[8];
    const float* b_val  = (const float*)d_in[9];
    const float* W_out  = (const float*)d_in[10];
    const float* b_out  = (const float*)d_in[11];

    char* wsp = (char*)d_ws;
    size_t o = 0;
    auto carve = [&](size_t bytes) -> void* {
        void* p = wsp + o; o += (bytes + 255) & ~(size_t)255; return p;
    };
    unsigned short* Wt_val = (unsigned short*)carve(256 * 256 * 2);
    unsigned short* Wt_out = (unsigned short*)carve(256 * 256 * 2);
    unsigned short* Wt_qa  = (unsigned short*)carve(384 * 256 * 2);
    float*          b_qa   = (float*)carve(384 * 4);
    unsigned short* v_buf  = (unsigned short*)carve((size_t)BS * NH * NV * 32 * 2);
    float*          oa_buf = (float*)carve((size_t)BS * NQ * 384 * 4);
    unsigned short* t_buf  = (unsigned short*)carve((size_t)BS * NQ * EMBED * 2);

    msda_prep_k<<<896, 256, 0, stream>>>(W_val, W_out, W_off, W_attn,
                                         b_off, b_attn, Wt_val, Wt_out, Wt_qa, b_qa);

    // merged: 1662 value blocks + 750 qa blocks; 3x12KB pipeline LDS (36KB -> 4 blk/CU)
    msda_gemm_vq_k<<<1662 + 750, 256, 36864, stream>>>(value, query, Wt_val, Wt_qa,
                                                       b_val, b_qa, v_buf, oa_buf);
    // sampler reads oa_buf + v_buf([b][h][pix][32]), writes t_buf
    msda_sampler_k<<<(BS * NQ) / 4, 256, 0, stream>>>(refpts, oa_buf, v_buf, t_buf);
    // out GEMM: 250 m-tiles x 2 n-tiles, reg-staged bf16 A
    msda_gemm_out_k<<<500, 256, 36864, stream>>>(t_buf, Wt_out, b_out, (float*)d_out);
}